// Round 1
// 79.657 us; speedup vs baseline: 1.6056x; 1.6056x over previous
//
#include <hip/hip_runtime.h>
#include <hip/hip_bf16.h>

// Problem: B=512, S=256, E=384, H=64.
// d_in: x [B,S,E] f32; Wq,Wk,Wv [E,H] f32.  d_out: [B,S,H] f32.
// ws: [0, 262144) wfrag bf16 (only region used).
//
// FUSED design: one block per batch. Projection (Q,K,V = x @ W) lands
// directly in LDS (swizzled), attention runs from LDS. Removes the 100 MB
// q/k/v HBM round-trip, the 4x per-batch K/V re-staging, and one launch.

#define NB   512
#define SS   256
#define EE   384
#define HH   64

#define PR   32          // x rows staged per chunk
#define LROW 392         // staging row stride in shorts (384 data + 8 pad)
#define XLSZ (PR * LROW) // 12544 shorts per staging buffer

typedef short bf16x8 __attribute__((ext_vector_type(8)));
typedef float f32x4  __attribute__((ext_vector_type(4)));

__device__ __forceinline__ short f2bf(float f) {
  union { float f; unsigned u; } x; x.f = f;
  unsigned r = x.u + 0x7fffu + ((x.u >> 16) & 1u);
  return (short)(r >> 16);
}

// ---------------- prep: W -> fragment-ordered bf16 (unchanged) ----------------
// wfrag[((ks*12+nf)*64 + lane)*8 + j] = Wcat[ks*32 + (lane>>4)*8 + j][nf*16 + (lane&15)]
__global__ __launch_bounds__(256) void prep_w_kernel(
    const float* __restrict__ Wq, const float* __restrict__ Wk,
    const float* __restrict__ Wv, short* __restrict__ wfrag) {
  int t = blockIdx.x * 256 + threadIdx.x;
  if (t >= 12 * 12 * 64) return;
  int ks  = t / (12 * 64);
  int rem = t % (12 * 64);
  int nf  = rem / 64;
  int l   = rem % 64;
  int l15 = l & 15, lhi = l >> 4;
  int ncat = nf * 16 + l15;
  const float* W = (ncat < 64) ? Wq : (ncat < 128 ? Wk : Wv);
  int n = ncat & 63;
  short* dst = wfrag + (size_t)t * 8;
#pragma unroll
  for (int j = 0; j < 8; ++j) {
    int kk = ks * 32 + lhi * 8 + j;
    dst[j] = f2bf(W[kk * 64 + n]);
  }
}

// ---------------- fused: projection + causal attention, one block = one batch ----------------
// 256 threads = 4 waves. LDS 145 KB -> 1 block/CU (4 waves/CU, 512 VGPR/wave budget).
__global__ __launch_bounds__(256, 1) void fused_kernel(
    const float* __restrict__ x, const short* __restrict__ wfrag,
    float* __restrict__ out) {
  // Q/K row-major swizzled: elem (row,h) at [row*64 + (h ^ ((row&7)<<3))]
  // V transposed swizzled:  elem (h,row) at [h*256 + (row ^ ((h&7)<<3))]
  __shared__ short Ql[SS * HH];          // 32 KB
  __shared__ short Kl[SS * HH];          // 32 KB
  __shared__ short Vt[HH * SS];          // 32 KB
  __shared__ short scratch[2 * XLSZ];    // 49 KB: x-staging dbuf, then P slabs

  int b    = blockIdx.x;
  int tid  = threadIdx.x;
  int lane = tid & 63, wv = tid >> 6;
  int l15  = lane & 15, lhi = lane >> 4;
  const float* xb = x + (size_t)b * SS * EE;

  // ---- W fragments resident in registers (36 x bf16x8 = 144 VGPR per wave) ----
  bf16x8 af[12][3];
#pragma unroll
  for (int ks = 0; ks < 12; ++ks)
#pragma unroll
    for (int h = 0; h < 3; ++h)
      af[ks][h] = *(const bf16x8*)(wfrag + ((size_t)(ks * 12 + wv * 3 + h) * 64 + lane) * 8);

  f32x4 st[12];

  auto loadch = [&](int ch) {  // global -> regs, fully contiguous
    const float* p0 = xb + (size_t)ch * PR * EE;
#pragma unroll
    for (int i = 0; i < 6; ++i) {
      const f32x4* p = (const f32x4*)(p0 + (size_t)(tid + 256 * i) * 8);
      st[2 * i]     = p[0];
      st[2 * i + 1] = p[1];
    }
  };
  auto writech = [&](short* xl) {  // regs -> bf16 -> padded LDS tile
#pragma unroll
    for (int i = 0; i < 6; ++i) {
      int c = tid + 256 * i;           // chunk of 8 floats: row = c/48, cg = c%48
      int row = c / 48, cg = c % 48;
      union { bf16x8 vv; __hip_bfloat162 h2[4]; } u;
      u.h2[0] = __float22bfloat162_rn(make_float2(st[2*i][0],   st[2*i][1]));
      u.h2[1] = __float22bfloat162_rn(make_float2(st[2*i][2],   st[2*i][3]));
      u.h2[2] = __float22bfloat162_rn(make_float2(st[2*i+1][0], st[2*i+1][1]));
      u.h2[3] = __float22bfloat162_rn(make_float2(st[2*i+1][2], st[2*i+1][3]));
      *(bf16x8*)(xl + row * LROW + cg * 8) = u.vv;
    }
  };

  // ---- projection: 8 chunks of 32 rows, register-dbuf'd loads, 1 barrier/chunk ----
  loadch(0);
  writech(scratch);                        // chunk 0 -> buffer 0

  for (int ch = 0; ch < 8; ++ch) {
    __syncthreads();                       // buffer (ch&1) ready; prev readers of (ch+1)&1 done
    if (ch < 7) loadch(ch + 1);            // issue next chunk's loads, overlap with MFMAs
    const short* xl = scratch + (ch & 1) * XLSZ;

    f32x4 acc[2][3];
#pragma unroll
    for (int rt = 0; rt < 2; ++rt)
#pragma unroll
      for (int h = 0; h < 3; ++h) acc[rt][h] = (f32x4){0.f, 0.f, 0.f, 0.f};

#pragma unroll
    for (int ks = 0; ks < 12; ++ks) {
      bf16x8 bx[2];
#pragma unroll
      for (int rt = 0; rt < 2; ++rt)
        bx[rt] = *(const bf16x8*)(xl + (rt * 16 + l15) * LROW + ks * 32 + lhi * 8);
#pragma unroll
      for (int rt = 0; rt < 2; ++rt)
#pragma unroll
        for (int h = 0; h < 3; ++h)
          acc[rt][h] = __builtin_amdgcn_mfma_f32_16x16x32_bf16(af[ks][h], bx[rt], acc[rt][h], 0, 0, 0);
    }

    // epilogue -> LDS. ncat = wv*48 + lhi*4 + ht*16 (uniform region per wv,ht)
    int ncb = wv * 48 + lhi * 4;
#pragma unroll
    for (int ht = 0; ht < 3; ++ht) {
      int ncat = ncb + ht * 16;
#pragma unroll
      for (int rt = 0; rt < 2; ++rt) {
        int row = ch * 32 + rt * 16 + l15;
        if (ncat < 128) {                  // Q or K: swizzled short4 store
          short* dst = (ncat < 64) ? Ql : Kl;
          int col = ncat & 63;             // 4-aligned; XOR flips bits>=3 -> contiguity kept
          union { short4 s4; __hip_bfloat162 h2[2]; } o;
          o.h2[0] = __float22bfloat162_rn(make_float2(acc[rt][ht][0], acc[rt][ht][1]));
          o.h2[1] = __float22bfloat162_rn(make_float2(acc[rt][ht][2], acc[rt][ht][3]));
          *(short4*)(dst + row * 64 + (col ^ ((row & 7) << 3))) = o.s4;
        } else {                           // V: transposed scalar stores
#pragma unroll
          for (int j = 0; j < 4; ++j) {
            int h = ncat - 128 + j;
            Vt[h * 256 + (row ^ ((h & 7) << 3))] = f2bf(acc[rt][ht][j]);
          }
        }
      }
    }
    if (ch < 7) writech(scratch + ((ch + 1) & 1) * XLSZ);
  }
  __syncthreads();                         // Ql/Kl/Vt complete; scratch (xl) dead

  // ---- attention: wave wv owns striped row-tiles rt = wv, wv+4, wv+8, wv+12 ----
  short* P = scratch + wv * (16 * 256);    // per-wave P slab (8 KB), aliases dead xl
  size_t obase = (size_t)b * SS * HH;

#pragma unroll
  for (int u = 0; u < 4; ++u) {
    int rt    = wv + 4 * u;
    int qrow0 = rt * 16;
    int twp   = (rt + 2) & ~1;             // causal tiles rt+1, padded to even

    // Q A-fragments from swizzled Ql
    bf16x8 qa[2];
#pragma unroll
    for (int kf = 0; kf < 2; ++kf) {
      int row = qrow0 + l15;
      qa[kf] = *(const bf16x8*)(Ql + row * 64 + ((kf * 32 + lhi * 8) ^ ((row & 7) << 3)));
    }

    // scores: S = (Q K^T) * 0.125, 16-col tiles
    f32x4 s[16];
#pragma unroll
    for (int t = 0; t < 16; ++t) {
      if (t >= twp) continue;
      int kc = t * 16 + l15;
      bf16x8 kb0 = *(const bf16x8*)(Kl + kc * 64 + ((lhi * 8)      ^ ((kc & 7) << 3)));
      bf16x8 kb1 = *(const bf16x8*)(Kl + kc * 64 + ((32 + lhi * 8) ^ ((kc & 7) << 3)));
      f32x4 a = (f32x4){0.f, 0.f, 0.f, 0.f};
      a = __builtin_amdgcn_mfma_f32_16x16x32_bf16(qa[0], kb0, a, 0, 0, 0);
      a = __builtin_amdgcn_mfma_f32_16x16x32_bf16(qa[1], kb1, a, 0, 0, 0);
      s[t] = a;
    }

    // causal mask + wave-parallel softmax (rows live in 16-lane groups)
#pragma unroll
    for (int t = 0; t < 16; ++t) {
      if (t >= twp) continue;
      int col = t * 16 + l15;
#pragma unroll
      for (int r = 0; r < 4; ++r) {
        int qg = qrow0 + lhi * 4 + r;
        float val = s[t][r] * 0.125f;
        s[t][r] = (col > qg) ? -INFINITY : val;
      }
    }
    float mx[4], sm[4], inv[4];
#pragma unroll
    for (int r = 0; r < 4; ++r) mx[r] = -INFINITY;
#pragma unroll
    for (int t = 0; t < 16; ++t) {
      if (t >= twp) continue;
#pragma unroll
      for (int r = 0; r < 4; ++r) mx[r] = fmaxf(mx[r], s[t][r]);
    }
#pragma unroll
    for (int r = 0; r < 4; ++r) {
      mx[r] = fmaxf(mx[r], __shfl_xor(mx[r], 1));
      mx[r] = fmaxf(mx[r], __shfl_xor(mx[r], 2));
      mx[r] = fmaxf(mx[r], __shfl_xor(mx[r], 4));
      mx[r] = fmaxf(mx[r], __shfl_xor(mx[r], 8));
      sm[r] = 0.f;
    }
#pragma unroll
    for (int t = 0; t < 16; ++t) {
      if (t >= twp) continue;
#pragma unroll
      for (int r = 0; r < 4; ++r) {
        float p = __expf(s[t][r] - mx[r]);   // exp(-inf)=0
        s[t][r] = p;
        sm[r] += p;
      }
    }
#pragma unroll
    for (int r = 0; r < 4; ++r) {
      sm[r] += __shfl_xor(sm[r], 1);
      sm[r] += __shfl_xor(sm[r], 2);
      sm[r] += __shfl_xor(sm[r], 4);
      sm[r] += __shfl_xor(sm[r], 8);
      inv[r] = 1.f / sm[r];
    }

    // P (bf16) into per-wave slab, swizzled
#pragma unroll
    for (int t = 0; t < 16; ++t) {
      if (t >= twp) continue;
#pragma unroll
      for (int r = 0; r < 4; ++r) {
        int row = lhi * 4 + r;
        int col = t * 16 + l15;
        P[row * 256 + (col ^ ((row & 7) << 3))] = f2bf(s[t][r]);
      }
    }

    // PV: out = P @ V
    f32x4 o[4];
#pragma unroll
    for (int nf = 0; nf < 4; ++nf) o[nf] = (f32x4){0.f, 0.f, 0.f, 0.f};
    int nk = twp >> 1;
#pragma unroll
    for (int kc2 = 0; kc2 < 8; ++kc2) {
      if (kc2 >= nk) continue;
      int kofs = kc2 * 32 + lhi * 8;
      bf16x8 pa = *(const bf16x8*)(P + l15 * 256 + (kofs ^ ((l15 & 7) << 3)));
#pragma unroll
      for (int nf = 0; nf < 4; ++nf) {
        int hrow = nf * 16 + l15;
        bf16x8 vb = *(const bf16x8*)(Vt + hrow * 256 + (kofs ^ ((hrow & 7) << 3)));
        o[nf] = __builtin_amdgcn_mfma_f32_16x16x32_bf16(pa, vb, o[nf], 0, 0, 0);
      }
    }

    // store (divide by row sum here)
#pragma unroll
    for (int nf = 0; nf < 4; ++nf)
#pragma unroll
      for (int r = 0; r < 4; ++r) {
        int qg = qrow0 + lhi * 4 + r;
        int h  = nf * 16 + l15;
        out[obase + (size_t)qg * HH + h] = o[nf][r] * inv[r];
      }
  }
}

extern "C" void kernel_launch(void* const* d_in, const int* in_sizes, int n_in,
                              void* d_out, int out_size, void* d_ws, size_t ws_size,
                              hipStream_t stream) {
  const float* x  = (const float*)d_in[0];
  const float* Wq = (const float*)d_in[1];
  const float* Wk = (const float*)d_in[2];
  const float* Wv = (const float*)d_in[3];
  float* out = (float*)d_out;

  short* wfrag = (short*)d_ws;

  prep_w_kernel<<<36, 256, 0, stream>>>(Wq, Wk, Wv, wfrag);
  fused_kernel<<<512, 256, 0, stream>>>(x, wfrag, out);
}

// Round 2
// 61.910 us; speedup vs baseline: 2.0659x; 1.2867x over previous
//
#include <hip/hip_runtime.h>
#include <hip/hip_bf16.h>

// Problem: B=512, S=256, E=384, H=64.
// d_in: x [B,S,E] f32; Wq,Wk,Wv [E,H] f32.  d_out: [B,S,H] f32.
// ws: [0, 262144) wfrag bf16 (only region used).
//
// FUSED, 8-wave version: one block per batch, 512 threads = 8 waves
// -> 2 waves/SIMD for latency hiding (was 1). Projection row-splits into
// 2 groups of 4 waves (16-row staging chunks, dbuf per group, 49 KB total
// scratch -- same LDS footprint as before). Attention: wave wv owns tiles
// {wv, 15-wv} -> perfectly balanced causal work (17 col-tiles each).

#define NB   512
#define SS   256
#define EE   384
#define HH   64

#define PR16  16          // x rows staged per chunk per group
#define LROW  392         // staging row stride in shorts (384 data + 8 pad)
#define XLSZ  (PR16 * LROW) // 6272 shorts per staging buffer

typedef short bf16x8 __attribute__((ext_vector_type(8)));
typedef float f32x4  __attribute__((ext_vector_type(4)));

__device__ __forceinline__ short f2bf(float f) {
  union { float f; unsigned u; } x; x.f = f;
  unsigned r = x.u + 0x7fffu + ((x.u >> 16) & 1u);
  return (short)(r >> 16);
}

// ---------------- prep: W -> fragment-ordered bf16 (unchanged) ----------------
// wfrag[((ks*12+nf)*64 + lane)*8 + j] = Wcat[ks*32 + (lane>>4)*8 + j][nf*16 + (lane&15)]
__global__ __launch_bounds__(256) void prep_w_kernel(
    const float* __restrict__ Wq, const float* __restrict__ Wk,
    const float* __restrict__ Wv, short* __restrict__ wfrag) {
  int t = blockIdx.x * 256 + threadIdx.x;
  if (t >= 12 * 12 * 64) return;
  int ks  = t / (12 * 64);
  int rem = t % (12 * 64);
  int nf  = rem / 64;
  int l   = rem % 64;
  int l15 = l & 15, lhi = l >> 4;
  int ncat = nf * 16 + l15;
  const float* W = (ncat < 64) ? Wq : (ncat < 128 ? Wk : Wv);
  int n = ncat & 63;
  short* dst = wfrag + (size_t)t * 8;
#pragma unroll
  for (int j = 0; j < 8; ++j) {
    int kk = ks * 32 + lhi * 8 + j;
    dst[j] = f2bf(W[kk * 64 + n]);
  }
}

// ---------------- fused: projection + causal attention, one block = one batch ----------------
// 512 threads = 8 waves, LDS 148480 B -> 1 block/CU, 2 waves/SIMD.
__global__ __launch_bounds__(512, 2) void fused_kernel(
    const float* __restrict__ x, const short* __restrict__ wfrag,
    float* __restrict__ out) {
  // Q/K row-major swizzled: elem (row,h) at [row*64 + (h ^ ((row&7)<<3))]
  // V transposed swizzled:  elem (h,row) at [h*256 + (row ^ ((h&7)<<3))]
  __shared__ short Ql[SS * HH];          // 32 KB
  __shared__ short Kl[SS * HH];          // 32 KB
  __shared__ short Vt[HH * SS];          // 32 KB
  __shared__ short scratch[4 * XLSZ];    // 49 KB: 2 groups x dbuf, then P slabs

  int b    = blockIdx.x;
  int tid  = threadIdx.x;
  int lane = tid & 63, wv = tid >> 6;
  int l15  = lane & 15, lhi = lane >> 4;
  int g    = wv >> 2;                    // row group: rows [g*128, g*128+128)
  int wg   = wv & 3;                     // column-split role within group
  int tg   = tid & 255;                  // thread index within group
  const float* xg = x + (size_t)b * SS * EE + (size_t)g * 128 * EE;

  // ---- W fragments resident in registers (36 x bf16x8 = 144 VGPR per wave) ----
  bf16x8 af[12][3];
#pragma unroll
  for (int ks = 0; ks < 12; ++ks)
#pragma unroll
    for (int h = 0; h < 3; ++h)
      af[ks][h] = *(const bf16x8*)(wfrag + ((size_t)(ks * 12 + wg * 3 + h) * 64 + lane) * 8);

  f32x4 st[6];

  auto loadch = [&](int ch) {  // global -> regs, fully contiguous (16 rows = 24 KB/group)
    const float* p0 = xg + (size_t)ch * (PR16 * EE);
#pragma unroll
    for (int i = 0; i < 3; ++i) {
      const f32x4* p = (const f32x4*)(p0 + (size_t)(tg + 256 * i) * 8);
      st[2 * i]     = p[0];
      st[2 * i + 1] = p[1];
    }
  };
  auto writech = [&](short* xl) {  // regs -> bf16 -> padded LDS tile
#pragma unroll
    for (int i = 0; i < 3; ++i) {
      int c = tg + 256 * i;            // chunk of 8 floats: row = c/48, cg = c%48
      int row = c / 48, cg = c % 48;
      union { bf16x8 vv; __hip_bfloat162 h2[4]; } u;
      u.h2[0] = __float22bfloat162_rn(make_float2(st[2*i][0],   st[2*i][1]));
      u.h2[1] = __float22bfloat162_rn(make_float2(st[2*i][2],   st[2*i][3]));
      u.h2[2] = __float22bfloat162_rn(make_float2(st[2*i+1][0], st[2*i+1][1]));
      u.h2[3] = __float22bfloat162_rn(make_float2(st[2*i+1][2], st[2*i+1][3]));
      *(bf16x8*)(xl + row * LROW + cg * 8) = u.vv;
    }
  };

  // ---- projection: 8 chunks of 16 rows per group, register-dbuf'd, 1 barrier/chunk ----
  loadch(0);
  writech(scratch + (g * 2) * XLSZ);     // chunk 0 -> group buffer 0

  for (int ch = 0; ch < 8; ++ch) {
    __syncthreads();                     // buffer (ch&1) ready; prev readers of other done
    if (ch < 7) loadch(ch + 1);          // issue next chunk's loads, overlap with MFMAs
    const short* xl = scratch + (g * 2 + (ch & 1)) * XLSZ;

    f32x4 acc[3];
#pragma unroll
    for (int h = 0; h < 3; ++h) acc[h] = (f32x4){0.f, 0.f, 0.f, 0.f};

#pragma unroll
    for (int ks = 0; ks < 12; ++ks) {
      bf16x8 bx = *(const bf16x8*)(xl + l15 * LROW + ks * 32 + lhi * 8);
#pragma unroll
      for (int h = 0; h < 3; ++h)
        acc[h] = __builtin_amdgcn_mfma_f32_16x16x32_bf16(af[ks][h], bx, acc[h], 0, 0, 0);
    }

    // epilogue -> LDS. ncat = wg*48 + lhi*4 + ht*16, row = g*128 + ch*16 + l15
    int ncb = wg * 48 + lhi * 4;
    int row = g * 128 + ch * PR16 + l15;
#pragma unroll
    for (int ht = 0; ht < 3; ++ht) {
      int ncat = ncb + ht * 16;
      if (ncat < 128) {                  // Q or K: swizzled short4 store
        short* dst = (ncat < 64) ? Ql : Kl;
        int col = ncat & 63;             // 4-aligned; XOR flips bits>=3 -> contiguity kept
        union { short4 s4; __hip_bfloat162 h2[2]; } o;
        o.h2[0] = __float22bfloat162_rn(make_float2(acc[ht][0], acc[ht][1]));
        o.h2[1] = __float22bfloat162_rn(make_float2(acc[ht][2], acc[ht][3]));
        *(short4*)(dst + row * 64 + (col ^ ((row & 7) << 3))) = o.s4;
      } else {                           // V: transposed scalar stores
#pragma unroll
        for (int j = 0; j < 4; ++j) {
          int h = ncat - 128 + j;
          Vt[h * 256 + (row ^ ((h & 7) << 3))] = f2bf(acc[ht][j]);
        }
      }
    }
    if (ch < 7) writech(scratch + (g * 2 + ((ch + 1) & 1)) * XLSZ);
  }
  __syncthreads();                       // Ql/Kl/Vt complete; staging dead

  // ---- attention: wave wv owns tiles {wv, 15-wv} (17 causal col-tiles each) ----
  // Hoist Q fragments for BOTH tiles before Ql is reused as P space.
  bf16x8 qa[2][2];
#pragma unroll
  for (int u = 0; u < 2; ++u) {
    int rt  = (u == 0) ? wv : (15 - wv);
    int row = rt * 16 + l15;
#pragma unroll
    for (int kf = 0; kf < 2; ++kf)
      qa[u][kf] = *(const bf16x8*)(Ql + row * 64 + ((kf * 32 + lhi * 8) ^ ((row & 7) << 3)));
  }
  __syncthreads();                       // all Q reads done before Ql aliased as P

  // P slabs: 8 KB per wave. Waves 0-5 in scratch, waves 6-7 in dead Ql.
  short* P = (wv < 6) ? (scratch + wv * (16 * 256)) : (Ql + (wv - 6) * (16 * 256));
  size_t obase = (size_t)b * SS * HH;

#pragma unroll
  for (int u = 0; u < 2; ++u) {
    int rt    = (u == 0) ? wv : (15 - wv);
    int qrow0 = rt * 16;
    int twp   = (rt + 2) & ~1;           // causal tiles rt+1, padded to even

    // scores: S = (Q K^T) * 0.125, 16-col tiles
    f32x4 s[16];
#pragma unroll
    for (int t = 0; t < 16; ++t) {
      if (t >= twp) continue;
      int kc = t * 16 + l15;
      bf16x8 kb0 = *(const bf16x8*)(Kl + kc * 64 + ((lhi * 8)      ^ ((kc & 7) << 3)));
      bf16x8 kb1 = *(const bf16x8*)(Kl + kc * 64 + ((32 + lhi * 8) ^ ((kc & 7) << 3)));
      f32x4 a = (f32x4){0.f, 0.f, 0.f, 0.f};
      a = __builtin_amdgcn_mfma_f32_16x16x32_bf16(qa[u][0], kb0, a, 0, 0, 0);
      a = __builtin_amdgcn_mfma_f32_16x16x32_bf16(qa[u][1], kb1, a, 0, 0, 0);
      s[t] = a;
    }

    // causal mask + wave-parallel softmax (rows live in 16-lane groups)
#pragma unroll
    for (int t = 0; t < 16; ++t) {
      if (t >= twp) continue;
      int col = t * 16 + l15;
#pragma unroll
      for (int r = 0; r < 4; ++r) {
        int qg = qrow0 + lhi * 4 + r;
        float val = s[t][r] * 0.125f;
        s[t][r] = (col > qg) ? -INFINITY : val;
      }
    }
    float mx[4], sm[4], inv[4];
#pragma unroll
    for (int r = 0; r < 4; ++r) mx[r] = -INFINITY;
#pragma unroll
    for (int t = 0; t < 16; ++t) {
      if (t >= twp) continue;
#pragma unroll
      for (int r = 0; r < 4; ++r) mx[r] = fmaxf(mx[r], s[t][r]);
    }
#pragma unroll
    for (int r = 0; r < 4; ++r) {
      mx[r] = fmaxf(mx[r], __shfl_xor(mx[r], 1));
      mx[r] = fmaxf(mx[r], __shfl_xor(mx[r], 2));
      mx[r] = fmaxf(mx[r], __shfl_xor(mx[r], 4));
      mx[r] = fmaxf(mx[r], __shfl_xor(mx[r], 8));
      sm[r] = 0.f;
    }
#pragma unroll
    for (int t = 0; t < 16; ++t) {
      if (t >= twp) continue;
#pragma unroll
      for (int r = 0; r < 4; ++r) {
        float p = __expf(s[t][r] - mx[r]);   // exp(-inf)=0
        s[t][r] = p;
        sm[r] += p;
      }
    }
#pragma unroll
    for (int r = 0; r < 4; ++r) {
      sm[r] += __shfl_xor(sm[r], 1);
      sm[r] += __shfl_xor(sm[r], 2);
      sm[r] += __shfl_xor(sm[r], 4);
      sm[r] += __shfl_xor(sm[r], 8);
      inv[r] = 1.f / sm[r];
    }

    // P (bf16) into per-wave slab, swizzled
#pragma unroll
    for (int t = 0; t < 16; ++t) {
      if (t >= twp) continue;
#pragma unroll
      for (int r = 0; r < 4; ++r) {
        int row = lhi * 4 + r;
        int col = t * 16 + l15;
        P[row * 256 + (col ^ ((row & 7) << 3))] = f2bf(s[t][r]);
      }
    }

    // PV: out = P @ V
    f32x4 o[4];
#pragma unroll
    for (int nf = 0; nf < 4; ++nf) o[nf] = (f32x4){0.f, 0.f, 0.f, 0.f};
    int nk = twp >> 1;
#pragma unroll
    for (int kc2 = 0; kc2 < 8; ++kc2) {
      if (kc2 >= nk) continue;
      int kofs = kc2 * 32 + lhi * 8;
      bf16x8 pa = *(const bf16x8*)(P + l15 * 256 + (kofs ^ ((l15 & 7) << 3)));
#pragma unroll
      for (int nf = 0; nf < 4; ++nf) {
        int hrow = nf * 16 + l15;
        bf16x8 vb = *(const bf16x8*)(Vt + hrow * 256 + (kofs ^ ((hrow & 7) << 3)));
        o[nf] = __builtin_amdgcn_mfma_f32_16x16x32_bf16(pa, vb, o[nf], 0, 0, 0);
      }
    }

    // store (divide by row sum here)
#pragma unroll
    for (int nf = 0; nf < 4; ++nf)
#pragma unroll
      for (int r = 0; r < 4; ++r) {
        int qg = qrow0 + lhi * 4 + r;
        int h  = nf * 16 + l15;
        out[obase + (size_t)qg * HH + h] = o[nf][r] * inv[r];
      }
  }
}

extern "C" void kernel_launch(void* const* d_in, const int* in_sizes, int n_in,
                              void* d_out, int out_size, void* d_ws, size_t ws_size,
                              hipStream_t stream) {
  const float* x  = (const float*)d_in[0];
  const float* Wq = (const float*)d_in[1];
  const float* Wk = (const float*)d_in[2];
  const float* Wv = (const float*)d_in[3];
  float* out = (float*)d_out;

  short* wfrag = (short*)d_ws;

  prep_w_kernel<<<36, 256, 0, stream>>>(Wq, Wk, Wv, wfrag);
  fused_kernel<<<512, 512, 0, stream>>>(x, wfrag, out);
}